// Round 4
// baseline (969.380 us; speedup 1.0000x reference)
//
#include <hip/hip_runtime.h>
#include <hip/hip_bf16.h>
#include <cstdint>

// GraphSAGE 2-layer, MI355X.
//  - CSR build (by dst): count -> scan -> fill (fill consumes cnt via atomic decrement).
//  - Fused mega-kernel per 128-row panel: gather-mean(x) -> LDS, GEMM1 (K=256, [agg|x]) in LDS,
//    h^T written back to same LDS, GEMM2 (K=128 -> 80 cols: hl | hrb) -- agg/h never hit global.
//  - out = log_softmax(mean_gather(hl) + hrb)   [transform-before-aggregate: mean is linear]
//  Workspace: 14.5 MB total (cnt, rowptr, part, col, hl[bf16]). hrb lives in d_out.

#define N_NODES 100000
#define N_EDGES 1600000
#define SCAN_B ((N_NODES + 1023) / 1024) // 98

// ---------------- CSR build ----------------
__global__ __launch_bounds__(256) void k_count(const int* __restrict__ dst,
                                               int* __restrict__ cnt) {
  int stride = gridDim.x * blockDim.x;
  for (int e = blockIdx.x * blockDim.x + threadIdx.x; e < N_EDGES; e += stride)
    atomicAdd(&cnt[dst[e]], 1);
}

__global__ __launch_bounds__(256) void k_scan1(const int* __restrict__ cnt,
                                               int* __restrict__ part) {
  __shared__ int ts[256];
  int tid = threadIdx.x;
  int base = blockIdx.x * 1024 + tid * 4;
  int s = 0;
#pragma unroll
  for (int j = 0; j < 4; ++j) { int i = base + j; if (i < N_NODES) s += cnt[i]; }
  ts[tid] = s; __syncthreads();
  for (int off = 128; off > 0; off >>= 1) {
    if (tid < off) ts[tid] += ts[tid + off];
    __syncthreads();
  }
  if (tid == 0) part[blockIdx.x] = ts[0];
}

__global__ __launch_bounds__(128) void k_scan2(int* __restrict__ part) {
  __shared__ int ts[128];
  int tid = threadIdx.x;
  int v = (tid < SCAN_B) ? part[tid] : 0;
  ts[tid] = v; __syncthreads();
  for (int off = 1; off < 128; off <<= 1) {
    int add = (tid >= off) ? ts[tid - off] : 0;
    __syncthreads();
    ts[tid] += add;
    __syncthreads();
  }
  if (tid < SCAN_B) part[tid] = ts[tid] - v; // exclusive block bases
}

__global__ __launch_bounds__(256) void k_scan3(const int* __restrict__ cnt,
                                               const int* __restrict__ part,
                                               int* __restrict__ rowptr) {
  __shared__ int ts[256];
  int tid = threadIdx.x;
  int base = blockIdx.x * 1024 + tid * 4;
  int v[4]; int tsum = 0;
#pragma unroll
  for (int j = 0; j < 4; ++j) { int i = base + j; v[j] = (i < N_NODES) ? cnt[i] : 0; tsum += v[j]; }
  ts[tid] = tsum; __syncthreads();
  for (int off = 1; off < 256; off <<= 1) {
    int add = (tid >= off) ? ts[tid - off] : 0;
    __syncthreads();
    ts[tid] += add;
    __syncthreads();
  }
  int run = part[blockIdx.x] + ts[tid] - tsum;
#pragma unroll
  for (int j = 0; j < 4; ++j) {
    int i = base + j;
    if (i < N_NODES) { run += v[j]; rowptr[i + 1] = run; }
  }
  if (blockIdx.x == 0 && tid == 0) rowptr[0] = 0;
}

// fill consumes cnt (atomic decrement) -> no cursor buffer needed; cnt ends all-zero
__global__ __launch_bounds__(256) void k_fill(const int* __restrict__ src,
                                              const int* __restrict__ dst,
                                              const int* __restrict__ rowptr,
                                              int* __restrict__ cnt,
                                              int* __restrict__ col) {
  int stride = gridDim.x * blockDim.x;
  for (int e = blockIdx.x * blockDim.x + threadIdx.x; e < N_EDGES; e += stride) {
    int d = dst[e];
    int old = atomicAdd(&cnt[d], -1); // old in [1, deg]
    col[rowptr[d] + old - 1] = src[e];
  }
}

// ---------------- fused: gather-mean + GEMM1(relu) + GEMM2, per 128-row panel ----------------
__global__ __launch_bounds__(512) void k_fused(const int* __restrict__ rowptr,
                                               const int* __restrict__ col,
                                               const float* __restrict__ x,
                                               const float* __restrict__ W1l,
                                               const float* __restrict__ W1r,
                                               const float* __restrict__ b1,
                                               const float* __restrict__ W2l,
                                               const float* __restrict__ W2r,
                                               const float* __restrict__ b2,
                                               __hip_bfloat16* __restrict__ hl,
                                               float* __restrict__ hrb) {
  __shared__ float Hs[128][132]; // phase1: agg tile [k][m]; phase2: h^T tile [k2][m]
  __shared__ float S1[32][132];  // x chunks [kk][m]
  __shared__ float S2[32][132];  // W1 / W2 chunks [kk][n]
  int tid = threadIdx.x;
  int row0 = blockIdx.x * 128;

  // ---- Phase 0: gather-mean into Hs[k][m] (wave per row, 16 rows/wave) ----
  {
    int wv = tid >> 6, lane = tid & 63;
    const float2* x2 = (const float2*)x;
    for (int r = 0; r < 16; ++r) {
      int m = wv * 16 + r;
      int gm = row0 + m;
      float2 a0 = make_float2(0.f, 0.f), a1 = make_float2(0.f, 0.f);
      float inv = 0.f;
      if (gm < N_NODES) {
        int s0 = rowptr[gm], s1 = rowptr[gm + 1];
        int e = s0;
        for (; e + 1 < s1; e += 2) {
          int sA = col[e], sB = col[e + 1];
          float2 vA = x2[(size_t)sA * 64 + lane];
          float2 vB = x2[(size_t)sB * 64 + lane];
          a0.x += vA.x; a0.y += vA.y;
          a1.x += vB.x; a1.y += vB.y;
        }
        if (e < s1) {
          float2 vA = x2[(size_t)col[e] * 64 + lane];
          a0.x += vA.x; a0.y += vA.y;
        }
        inv = 1.f / (float)max(s1 - s0, 1);
      }
      Hs[2 * lane + 0][m] = (a0.x + a1.x) * inv;
      Hs[2 * lane + 1][m] = (a0.y + a1.y) * inv;
    }
  }
  __syncthreads();

  // ---- Phase 1: GEMM1  h = relu([agg|x] @ [W1l|W1r]^T + b1) ----
  int tx = tid & 31, ty = tid >> 5; // n = tx*4+j (0..127), m = ty*8+i (0..127)
  float acc1[8][4] = {};
  for (int k0 = 0; k0 < 256; k0 += 32) {
    // stage W1 chunk -> S2[kk][n]
    const float* Wp = (k0 < 128) ? W1l : W1r;
    int kb = (k0 < 128) ? k0 : (k0 - 128);
#pragma unroll
    for (int r = 0; r < 2; ++r) {
      int idx = tid + r * 512;
      int n = idx >> 3, q = idx & 7;
      float4 v = *(const float4*)(Wp + n * 128 + kb + q * 4);
      S2[q * 4 + 0][n] = v.x; S2[q * 4 + 1][n] = v.y;
      S2[q * 4 + 2][n] = v.z; S2[q * 4 + 3][n] = v.w;
    }
    if (k0 >= 128) { // stage x chunk -> S1[kk][m]
#pragma unroll
      for (int r = 0; r < 2; ++r) {
        int idx = tid + r * 512;
        int m = idx >> 3, q = idx & 7;
        int gm = row0 + m; if (gm >= N_NODES) gm = N_NODES - 1;
        float4 v = *(const float4*)(x + (size_t)gm * 128 + (k0 - 128) + q * 4);
        S1[q * 4 + 0][m] = v.x; S1[q * 4 + 1][m] = v.y;
        S1[q * 4 + 2][m] = v.z; S1[q * 4 + 3][m] = v.w;
      }
    }
    __syncthreads();
#pragma unroll 4
    for (int k = 0; k < 32; ++k) {
      const float* arow = (k0 < 128) ? &Hs[k0 + k][0] : &S1[k][0];
      float a[8], b[4];
      *(float4*)&a[0] = *(const float4*)(arow + ty * 8);
      *(float4*)&a[4] = *(const float4*)(arow + ty * 8 + 4);
      *(float4*)&b[0] = *(const float4*)&S2[k][tx * 4];
#pragma unroll
      for (int i = 0; i < 8; ++i)
#pragma unroll
        for (int j = 0; j < 4; ++j)
          acc1[i][j] = fmaf(a[i], b[j], acc1[i][j]);
    }
    __syncthreads();
  }
  // epilogue: h^T back into Hs[n][m]  (all agg reads of Hs are past a barrier)
  {
    float4 bl = *(const float4*)(b1 + tx * 4);
    float bb[4] = {bl.x, bl.y, bl.z, bl.w};
#pragma unroll
    for (int j = 0; j < 4; ++j) {
      int n = tx * 4 + j;
      float4 lo, hi;
      lo.x = fmaxf(acc1[0][j] + bb[j], 0.f); lo.y = fmaxf(acc1[1][j] + bb[j], 0.f);
      lo.z = fmaxf(acc1[2][j] + bb[j], 0.f); lo.w = fmaxf(acc1[3][j] + bb[j], 0.f);
      hi.x = fmaxf(acc1[4][j] + bb[j], 0.f); hi.y = fmaxf(acc1[5][j] + bb[j], 0.f);
      hi.z = fmaxf(acc1[6][j] + bb[j], 0.f); hi.w = fmaxf(acc1[7][j] + bb[j], 0.f);
      *(float4*)&Hs[n][ty * 8] = lo;
      *(float4*)&Hs[n][ty * 8 + 4] = hi;
    }
  }

  // ---- Phase 2: GEMM2  [hl | hrb] = h @ [W2l|W2r]^T (+b2 on hrb), 80 cols ----
  int tx2 = tid & 15, ty2 = tid >> 4; // n2 = tx2*5+j (0..79), m = ty2*4+i (0..127)
  float acc2[4][5] = {};
  for (int k0 = 0; k0 < 128; k0 += 32) {
    // stage W2 chunk -> S2[kk][n2] (n2<40: W2l row, else W2r row)
#pragma unroll
    for (int r = 0; r < 2; ++r) {
      int idx = tid + r * 512;
      if (idx < 640) {
        int n2 = idx >> 3, q = idx & 7;
        const float* Bp = (n2 < 40) ? (W2l + n2 * 128) : (W2r + (n2 - 40) * 128);
        float4 v = *(const float4*)(Bp + k0 + q * 4);
        S2[q * 4 + 0][n2] = v.x; S2[q * 4 + 1][n2] = v.y;
        S2[q * 4 + 2][n2] = v.z; S2[q * 4 + 3][n2] = v.w;
      }
    }
    __syncthreads(); // also orders the Hs h^T writes before the first reads below
#pragma unroll 4
    for (int k = 0; k < 32; ++k) {
      float a[4], b[5];
      *(float4*)&a[0] = *(const float4*)&Hs[k0 + k][ty2 * 4];
#pragma unroll
      for (int j = 0; j < 5; ++j) b[j] = S2[k][tx2 * 5 + j];
#pragma unroll
      for (int i = 0; i < 4; ++i)
#pragma unroll
        for (int j = 0; j < 5; ++j)
          acc2[i][j] = fmaf(a[i], b[j], acc2[i][j]);
    }
    __syncthreads();
  }
#pragma unroll
  for (int j = 0; j < 5; ++j) {
    int n2 = tx2 * 5 + j;
    float bias = (n2 >= 40) ? b2[n2 - 40] : 0.f;
#pragma unroll
    for (int i = 0; i < 4; ++i) {
      int gm = row0 + ty2 * 4 + i;
      if (gm < N_NODES) {
        if (n2 < 40) hl[(size_t)gm * 40 + n2] = __float2bfloat16(acc2[i][j]);
        else         hrb[(size_t)gm * 40 + (n2 - 40)] = acc2[i][j] + bias;
      }
    }
  }
}

// ---------------- out = log_softmax(mean_gather(hl) + hrb), hrb aliases out ----------------
__global__ __launch_bounds__(256) void k_out(const int* __restrict__ rowptr,
                                             const int* __restrict__ col,
                                             const __hip_bfloat16* __restrict__ hl,
                                             const float* __restrict__ hrb,
                                             float* __restrict__ out) {
  int wid = (blockIdx.x * 256 + threadIdx.x) >> 6; // wave per node
  int lane = threadIdx.x & 63;
  if (wid >= N_NODES) return;
  int s0 = rowptr[wid], s1 = rowptr[wid + 1];
  float acc = 0.f;
  for (int e = s0; e < s1; ++e) {
    int s = col[e];
    if (lane < 40) acc += __bfloat162float(hl[(size_t)s * 40 + lane]);
  }
  float inv = 1.f / (float)max(s1 - s0, 1);
  float v = (lane < 40) ? (acc * inv + hrb[(size_t)wid * 40 + lane]) : -3.4e38f;
  float mv = v;
#pragma unroll
  for (int off = 32; off > 0; off >>= 1) mv = fmaxf(mv, __shfl_xor(mv, off));
  float ev = (lane < 40) ? __expf(v - mv) : 0.f;
  float sv = ev;
#pragma unroll
  for (int off = 32; off > 0; off >>= 1) sv += __shfl_xor(sv, off);
  if (lane < 40) out[(size_t)wid * 40 + lane] = v - mv - __logf(sv);
}

// ---------------- launch ----------------
extern "C" void kernel_launch(void* const* d_in, const int* in_sizes, int n_in,
                              void* d_out, int out_size, void* d_ws, size_t ws_size,
                              hipStream_t stream) {
  const float* x   = (const float*)d_in[0];
  const int* ei    = (const int*)d_in[1]; // harness stages integers as int32
  const float* W1l = (const float*)d_in[2];
  const float* b1  = (const float*)d_in[3];
  const float* W1r = (const float*)d_in[4];
  const float* W2l = (const float*)d_in[5];
  const float* b2  = (const float*)d_in[6];
  const float* W2r = (const float*)d_in[7];
  float* out = (float*)d_out;
  const int* src = ei;
  const int* dst = ei + N_EDGES;

  // workspace: 14.5 MB total
  char* w = (char*)d_ws;
  size_t off = 0;
  auto take = [&](size_t bytes) {
    void* p = w + off;
    off = (off + bytes + 255) & ~(size_t)255;
    return p;
  };
  int* cnt    = (int*)take((size_t)N_NODES * 4);          // zeroed; consumed by k_fill
  int* rowptr = (int*)take((size_t)(N_NODES + 1) * 4);
  int* part   = (int*)take(256 * 4);
  int* col    = (int*)take((size_t)N_EDGES * 4);
  __hip_bfloat16* hl = (__hip_bfloat16*)take((size_t)N_NODES * 40 * 2);
  float* hrb  = out; // gemm2 writes, k_out consumes+overwrites in place
  (void)ws_size; (void)in_sizes; (void)n_in; (void)out_size;

  hipMemsetAsync(cnt, 0, (size_t)N_NODES * 4, stream);

  k_count<<<2048, 256, 0, stream>>>(dst, cnt);
  k_scan1<<<SCAN_B, 256, 0, stream>>>(cnt, part);
  k_scan2<<<1, 128, 0, stream>>>(part);
  k_scan3<<<SCAN_B, 256, 0, stream>>>(cnt, part, rowptr);
  k_fill<<<2048, 256, 0, stream>>>(src, dst, rowptr, cnt, col);
  k_fused<<<(N_NODES + 127) / 128, 512, 0, stream>>>(rowptr, col, x, W1l, W1r, b1,
                                                     W2l, W2r, b2, hl, hrb);
  k_out<<<(N_NODES + 3) / 4, 256, 0, stream>>>(rowptr, col, hl, hrb, out);
}

// Round 11
// 586.944 us; speedup vs baseline: 1.6516x; 1.6516x over previous
//
#include <hip/hip_runtime.h>
#include <cstdint>

// GraphSAGE 2-layer, MI355X.
// Fast path (ws_size permitting, ~66.5 MB):
//   prep: x -> bf16 (xb), W1/W2 -> packed bf16 (w1b[n][256], w2b[n][128])
//   CSR build (count/scan/fill), k_aggb: wave-per-node bf16 mean-gather (no LDS, high occ)
//   k_mfma1: hb = relu([aggb|xb] @ w1b^T + b1)  (MFMA bf16, LDS-free; hb aliases xb)
//   k_mfma2: hl(bf16) | hrb(fp32->d_out) = hb @ w2b^T (+b2)
//   k_out  : out = log_softmax(mean_gather(hl) + hrb)   [transform-before-aggregate]
// Fallback path (small ws, ~14.5 MB): round-4 fused kernel (proven correct).

#define N_NODES 100000
#define N_EDGES 1600000
#define SCAN_B ((N_NODES + 1023) / 1024) // 98

typedef __attribute__((ext_vector_type(8))) short bf16x8;
typedef __attribute__((ext_vector_type(4))) float f32x4;

static __device__ __forceinline__ unsigned short f2bf(float f) { // RNE
  unsigned int u = __float_as_uint(f);
  return (unsigned short)((u + 0x7fffu + ((u >> 16) & 1u)) >> 16);
}
static __device__ __forceinline__ float bf2f(unsigned short s) {
  return __uint_as_float(((unsigned int)s) << 16);
}

// ---------------- CSR build ----------------
__global__ __launch_bounds__(256) void k_count(const int* __restrict__ dst,
                                               int* __restrict__ cnt) {
  int stride = gridDim.x * blockDim.x;
  for (int e = blockIdx.x * blockDim.x + threadIdx.x; e < N_EDGES; e += stride)
    atomicAdd(&cnt[dst[e]], 1);
}

__global__ __launch_bounds__(256) void k_scan1(const int* __restrict__ cnt,
                                               int* __restrict__ part) {
  __shared__ int ts[256];
  int tid = threadIdx.x;
  int base = blockIdx.x * 1024 + tid * 4;
  int s = 0;
#pragma unroll
  for (int j = 0; j < 4; ++j) { int i = base + j; if (i < N_NODES) s += cnt[i]; }
  ts[tid] = s; __syncthreads();
  for (int off = 128; off > 0; off >>= 1) {
    if (tid < off) ts[tid] += ts[tid + off];
    __syncthreads();
  }
  if (tid == 0) part[blockIdx.x] = ts[0];
}

__global__ __launch_bounds__(128) void k_scan2(int* __restrict__ part) {
  __shared__ int ts[128];
  int tid = threadIdx.x;
  int v = (tid < SCAN_B) ? part[tid] : 0;
  ts[tid] = v; __syncthreads();
  for (int off = 1; off < 128; off <<= 1) {
    int add = (tid >= off) ? ts[tid - off] : 0;
    __syncthreads();
    ts[tid] += add;
    __syncthreads();
  }
  if (tid < SCAN_B) part[tid] = ts[tid] - v;
}

__global__ __launch_bounds__(256) void k_scan3(const int* __restrict__ cnt,
                                               const int* __restrict__ part,
                                               int* __restrict__ rowptr) {
  __shared__ int ts[256];
  int tid = threadIdx.x;
  int base = blockIdx.x * 1024 + tid * 4;
  int v[4]; int tsum = 0;
#pragma unroll
  for (int j = 0; j < 4; ++j) { int i = base + j; v[j] = (i < N_NODES) ? cnt[i] : 0; tsum += v[j]; }
  ts[tid] = tsum; __syncthreads();
  for (int off = 1; off < 256; off <<= 1) {
    int add = (tid >= off) ? ts[tid - off] : 0;
    __syncthreads();
    ts[tid] += add;
    __syncthreads();
  }
  int run = part[blockIdx.x] + ts[tid] - tsum;
#pragma unroll
  for (int j = 0; j < 4; ++j) {
    int i = base + j;
    if (i < N_NODES) { run += v[j]; rowptr[i + 1] = run; }
  }
  if (blockIdx.x == 0 && tid == 0) rowptr[0] = 0;
}

__global__ __launch_bounds__(256) void k_fill(const int* __restrict__ src,
                                              const int* __restrict__ dst,
                                              const int* __restrict__ rowptr,
                                              int* __restrict__ cnt,
                                              int* __restrict__ col) {
  int stride = gridDim.x * blockDim.x;
  for (int e = blockIdx.x * blockDim.x + threadIdx.x; e < N_EDGES; e += stride) {
    int d = dst[e];
    int old = atomicAdd(&cnt[d], -1);
    col[rowptr[d] + old - 1] = src[e];
  }
}

// ---------------- fast path: prep ----------------
__global__ __launch_bounds__(256) void k_prepx(const float* __restrict__ x,
                                               unsigned short* __restrict__ xb) {
  int stride = gridDim.x * blockDim.x;
  const int total = N_NODES * 128 / 4;
  for (int i = blockIdx.x * blockDim.x + threadIdx.x; i < total; i += stride) {
    float4 v = ((const float4*)x)[i];
    ushort4 o;
    o.x = f2bf(v.x); o.y = f2bf(v.y); o.z = f2bf(v.z); o.w = f2bf(v.w);
    *(ushort4*)(xb + (size_t)i * 4) = o;
  }
}

// w1b[n][k], n<128, k<256 (k<128: W1l, else W1r); w2b[n][k], n<80, k<128 (n<40: W2l else W2r)
__global__ __launch_bounds__(256) void k_prepw(const float* __restrict__ W1l,
                                               const float* __restrict__ W1r,
                                               const float* __restrict__ W2l,
                                               const float* __restrict__ W2r,
                                               unsigned short* __restrict__ w1b,
                                               unsigned short* __restrict__ w2b) {
  int idx = blockIdx.x * 256 + threadIdx.x; // 168 blocks -> 43008 threads
  if (idx < 32768) {
    int n = idx >> 8, k = idx & 255;
    float v = (k < 128) ? W1l[n * 128 + k] : W1r[n * 128 + (k - 128)];
    w1b[idx] = f2bf(v);
  } else if (idx < 43008) {
    int j = idx - 32768;
    int n = j >> 7, k = j & 127;
    float v = (n < 40) ? W2l[n * 128 + k] : W2r[(n - 40) * 128 + k];
    w2b[j] = f2bf(v);
  }
}

// ---------------- fast path: bf16 mean-gather, wave per node ----------------
__global__ __launch_bounds__(256) void k_aggb(const int* __restrict__ rowptr,
                                              const int* __restrict__ col,
                                              const unsigned short* __restrict__ xb,
                                              unsigned short* __restrict__ aggb) {
  int wv = (blockIdx.x * 256 + threadIdx.x) >> 6;
  int lane = threadIdx.x & 63;
  if (wv >= N_NODES) return;
  int s0 = rowptr[wv], s1 = rowptr[wv + 1];
  const unsigned int* x2 = (const unsigned int*)xb; // 2 bf16 per lane
  float a0 = 0.f, a1 = 0.f, c0 = 0.f, c1 = 0.f;
  int e = s0;
  for (; e + 1 < s1; e += 2) {
    unsigned int uA = x2[(size_t)col[e] * 64 + lane];
    unsigned int uB = x2[(size_t)col[e + 1] * 64 + lane];
    a0 += __uint_as_float(uA << 16);
    a1 += __uint_as_float(uA & 0xffff0000u);
    c0 += __uint_as_float(uB << 16);
    c1 += __uint_as_float(uB & 0xffff0000u);
  }
  if (e < s1) {
    unsigned int uA = x2[(size_t)col[e] * 64 + lane];
    a0 += __uint_as_float(uA << 16);
    a1 += __uint_as_float(uA & 0xffff0000u);
  }
  float inv = 1.f / (float)max(s1 - s0, 1);
  unsigned int p = (unsigned int)f2bf((a0 + c0) * inv) |
                   ((unsigned int)f2bf((a1 + c1) * inv) << 16);
  ((unsigned int*)aggb)[(size_t)wv * 64 + lane] = p;
}

// ---------------- fast path: MFMA GEMM1  hb = relu([aggb|xb] @ w1b^T + b1) ----------------
// LDS-free: A/B fragments read straight from global (L1/L2-hot). hb aliases xb ->
// __syncthreads() separates all reads from all writes within the owning block;
// each block touches only its own 128-row panel (tail clamp stays in-panel).
__global__ __launch_bounds__(256) void k_mfma1(const unsigned short* __restrict__ aggb,
                                               const unsigned short* __restrict__ xb,
                                               const unsigned short* __restrict__ w1b,
                                               const float* __restrict__ b1,
                                               unsigned short* __restrict__ hb) {
  int tid = threadIdx.x;
  int wid = tid >> 6, lane = tid & 63;
  int wr = wid >> 1, wc = wid & 1;
  int lr = lane & 15, lg = lane >> 4;
  int row0 = blockIdx.x * 128 + wr * 64;
  int wn = wc * 64;

  size_t arow[4];
#pragma unroll
  for (int m = 0; m < 4; ++m) {
    int gm = row0 + m * 16 + lr;
    if (gm > N_NODES - 1) gm = N_NODES - 1;
    arow[m] = (size_t)gm * 128;
  }
  f32x4 acc[4][4] = {};
#pragma unroll
  for (int k0 = 0; k0 < 256; k0 += 32) {
    const unsigned short* ab = (k0 < 128) ? (aggb + k0) : (xb + (k0 - 128));
    bf16x8 a[4], b[4];
#pragma unroll
    for (int m = 0; m < 4; ++m)
      a[m] = *(const bf16x8*)(ab + arow[m] + lg * 8);
#pragma unroll
    for (int n = 0; n < 4; ++n)
      b[n] = *(const bf16x8*)(w1b + (size_t)(wn + n * 16 + lr) * 256 + k0 + lg * 8);
#pragma unroll
    for (int m = 0; m < 4; ++m)
#pragma unroll
      for (int n = 0; n < 4; ++n)
        acc[m][n] = __builtin_amdgcn_mfma_f32_16x16x32_bf16(a[m], b[n], acc[m][n], 0, 0, 0);
  }
  __syncthreads(); // hb aliases xb: drain all A reads before any write
  float bb[4];
#pragma unroll
  for (int n = 0; n < 4; ++n) bb[n] = b1[wn + n * 16 + lr];
#pragma unroll
  for (int m = 0; m < 4; ++m)
#pragma unroll
    for (int r = 0; r < 4; ++r) {
      int gm = row0 + m * 16 + lg * 4 + r; // C/D: row=(lane>>4)*4+reg, col=lane&15
      if (gm < N_NODES) {
#pragma unroll
        for (int n = 0; n < 4; ++n) {
          float v = fmaxf(acc[m][n][r] + bb[n], 0.f);
          hb[(size_t)gm * 128 + wn + n * 16 + lr] = f2bf(v);
        }
      }
    }
}

// ---------------- fast path: MFMA GEMM2  [hl | hrb] = hb @ w2b^T (+b2) ----------------
__global__ __launch_bounds__(256) void k_mfma2(const unsigned short* __restrict__ hb,
                                               const unsigned short* __restrict__ w2b,
                                               const float* __restrict__ b2,
                                               unsigned short* __restrict__ hl,
                                               float* __restrict__ outp) {
  int tid = threadIdx.x;
  int wid = tid >> 6, lane = tid & 63;
  int lr = lane & 15, lg = lane >> 4;
  int row0 = blockIdx.x * 256 + wid * 64;

  size_t arow[4];
#pragma unroll
  for (int m = 0; m < 4; ++m) {
    int gm = row0 + m * 16 + lr;
    if (gm > N_NODES - 1) gm = N_NODES - 1;
    arow[m] = (size_t)gm * 128;
  }
  f32x4 acc[4][5] = {};
#pragma unroll
  for (int k0 = 0; k0 < 128; k0 += 32) {
    bf16x8 a[4], b[5];
#pragma unroll
    for (int m = 0; m < 4; ++m)
      a[m] = *(const bf16x8*)(hb + arow[m] + k0 + lg * 8);
#pragma unroll
    for (int n = 0; n < 5; ++n)
      b[n] = *(const bf16x8*)(w2b + (size_t)(n * 16 + lr) * 128 + k0 + lg * 8);
#pragma unroll
    for (int m = 0; m < 4; ++m)
#pragma unroll
      for (int n = 0; n < 5; ++n)
        acc[m][n] = __builtin_amdgcn_mfma_f32_16x16x32_bf16(a[m], b[n], acc[m][n], 0, 0, 0);
  }
#pragma unroll
  for (int m = 0; m < 4; ++m)
#pragma unroll
    for (int r = 0; r < 4; ++r) {
      int gm = row0 + m * 16 + lg * 4 + r;
      if (gm < N_NODES) {
#pragma unroll
        for (int n = 0; n < 5; ++n) {
          int c = n * 16 + lr;
          float v = acc[m][n][r];
          if (c < 40) hl[(size_t)gm * 40 + c] = f2bf(v);
          else        outp[(size_t)gm * 40 + (c - 40)] = v + b2[c - 40];
        }
      }
    }
}

// ---------------- out = log_softmax(mean_gather(hl) + hrb), hrb aliases out ----------------
__global__ __launch_bounds__(256) void k_out(const int* __restrict__ rowptr,
                                             const int* __restrict__ col,
                                             const unsigned short* __restrict__ hl,
                                             const float* __restrict__ hrb,
                                             float* __restrict__ out) {
  int wid = (blockIdx.x * 256 + threadIdx.x) >> 6;
  int lane = threadIdx.x & 63;
  if (wid >= N_NODES) return;
  int s0 = rowptr[wid], s1 = rowptr[wid + 1];
  float acc = 0.f;
  for (int e = s0; e < s1; ++e) {
    int s = col[e];
    if (lane < 40) acc += bf2f(hl[(size_t)s * 40 + lane]);
  }
  float inv = 1.f / (float)max(s1 - s0, 1);
  float v = (lane < 40) ? (acc * inv + hrb[(size_t)wid * 40 + lane]) : -3.4e38f;
  float mv = v;
#pragma unroll
  for (int off = 32; off > 0; off >>= 1) mv = fmaxf(mv, __shfl_xor(mv, off));
  float ev = (lane < 40) ? __expf(v - mv) : 0.f;
  float sv = ev;
#pragma unroll
  for (int off = 32; off > 0; off >>= 1) sv += __shfl_xor(sv, off);
  if (lane < 40) out[(size_t)wid * 40 + lane] = v - mv - __logf(sv);
}

// ---------------- fallback: round-4 fused kernel (proven) ----------------
__global__ __launch_bounds__(512) void k_fused(const int* __restrict__ rowptr,
                                               const int* __restrict__ col,
                                               const float* __restrict__ x,
                                               const float* __restrict__ W1l,
                                               const float* __restrict__ W1r,
                                               const float* __restrict__ b1,
                                               const float* __restrict__ W2l,
                                               const float* __restrict__ W2r,
                                               const float* __restrict__ b2,
                                               unsigned short* __restrict__ hl,
                                               float* __restrict__ hrb) {
  __shared__ float Hs[128][132];
  __shared__ float S1[32][132];
  __shared__ float S2[32][132];
  int tid = threadIdx.x;
  int row0 = blockIdx.x * 128;
  {
    int wv = tid >> 6, lane = tid & 63;
    const float2* x2 = (const float2*)x;
    for (int r = 0; r < 16; ++r) {
      int m = wv * 16 + r;
      int gm = row0 + m;
      float2 a0 = make_float2(0.f, 0.f), a1 = make_float2(0.f, 0.f);
      float inv = 0.f;
      if (gm < N_NODES) {
        int s0 = rowptr[gm], s1 = rowptr[gm + 1];
        int e = s0;
        for (; e + 1 < s1; e += 2) {
          int sA = col[e], sB = col[e + 1];
          float2 vA = x2[(size_t)sA * 64 + lane];
          float2 vB = x2[(size_t)sB * 64 + lane];
          a0.x += vA.x; a0.y += vA.y;
          a1.x += vB.x; a1.y += vB.y;
        }
        if (e < s1) {
          float2 vA = x2[(size_t)col[e] * 64 + lane];
          a0.x += vA.x; a0.y += vA.y;
        }
        inv = 1.f / (float)max(s1 - s0, 1);
      }
      Hs[2 * lane + 0][m] = (a0.x + a1.x) * inv;
      Hs[2 * lane + 1][m] = (a0.y + a1.y) * inv;
    }
  }
  __syncthreads();
  int tx = tid & 31, ty = tid >> 5;
  float acc1[8][4] = {};
  for (int k0 = 0; k0 < 256; k0 += 32) {
    const float* Wp = (k0 < 128) ? W1l : W1r;
    int kb = (k0 < 128) ? k0 : (k0 - 128);
#pragma unroll
    for (int r = 0; r < 2; ++r) {
      int idx = tid + r * 512;
      int n = idx >> 3, q = idx & 7;
      float4 v = *(const float4*)(Wp + n * 128 + kb + q * 4);
      S2[q * 4 + 0][n] = v.x; S2[q * 4 + 1][n] = v.y;
      S2[q * 4 + 2][n] = v.z; S2[q * 4 + 3][n] = v.w;
    }
    if (k0 >= 128) {
#pragma unroll
      for (int r = 0; r < 2; ++r) {
        int idx = tid + r * 512;
        int m = idx >> 3, q = idx & 7;
        int gm = row0 + m; if (gm >= N_NODES) gm = N_NODES - 1;
        float4 v = *(const float4*)(x + (size_t)gm * 128 + (k0 - 128) + q * 4);
        S1[q * 4 + 0][m] = v.x; S1[q * 4 + 1][m] = v.y;
        S1[q * 4 + 2][m] = v.z; S1[q * 4 + 3][m] = v.w;
      }
    }
    __syncthreads();
#pragma unroll 4
    for (int k = 0; k < 32; ++k) {
      const float* arow = (k0 < 128) ? &Hs[k0 + k][0] : &S1[k][0];
      float a[8], b[4];
      *(float4*)&a[0] = *(const float4*)(arow + ty * 8);
      *(float4*)&a[4] = *(const float4*)(arow + ty * 8 + 4);
      *(float4*)&b[0] = *(const float4*)&S2[k][tx * 4];
#pragma unroll
      for (int i = 0; i < 8; ++i)
#pragma unroll
        for (int j = 0; j < 4; ++j)
          acc1[i][j] = fmaf(a[i], b[j], acc1[i][j]);
    }
    __syncthreads();
  }
  {
    float4 bl = *(const float4*)(b1 + tx * 4);
    float bb[4] = {bl.x, bl.y, bl.z, bl.w};
#pragma unroll
    for (int j = 0; j < 4; ++j) {
      int n = tx * 4 + j;
      float4 lo, hi;
      lo.x = fmaxf(acc1[0][j] + bb[j], 0.f); lo.y = fmaxf(acc1[1][j] + bb[j], 0.f);
      lo.z = fmaxf(acc1[2][j] + bb[j], 0.f); lo.w = fmaxf(acc1[3][j] + bb[j], 0.f);
      hi.x = fmaxf(acc1[4][j] + bb[j], 0.f); hi.y = fmaxf(acc1[5][j] + bb[j], 0.f);
      hi.z = fmaxf(acc1[6][j] + bb[j], 0.f); hi.w = fmaxf(acc1[7][j] + bb[j], 0.f);
      *(float4*)&Hs[n][ty * 8] = lo;
      *(float4*)&Hs[n][ty * 8 + 4] = hi;
    }
  }
  int tx2 = tid & 15, ty2 = tid >> 4;
  float acc2[4][5] = {};
  for (int k0 = 0; k0 < 128; k0 += 32) {
#pragma unroll
    for (int r = 0; r < 2; ++r) {
      int idx = tid + r * 512;
      if (idx < 640) {
        int n2 = idx >> 3, q = idx & 7;
        const float* Bp = (n2 < 40) ? (W2l + n2 * 128) : (W2r + (n2 - 40) * 128);
        float4 v = *(const float4*)(Bp + k0 + q * 4);
        S2[q * 4 + 0][n2] = v.x; S2[q * 4 + 1][n2] = v.y;
        S2[q * 4 + 2][n2] = v.z; S2[q * 4 + 3][n2] = v.w;
      }
    }
    __syncthreads();
#pragma unroll 4
    for (int k = 0; k < 32; ++k) {
      float a[4], b[5];
      *(float4*)&a[0] = *(const float4*)&Hs[k0 + k][ty2 * 4];
#pragma unroll
      for (int j = 0; j < 5; ++j) b[j] = S2[k][tx2 * 5 + j];
#pragma unroll
      for (int i = 0; i < 4; ++i)
#pragma unroll
        for (int j = 0; j < 5; ++j)
          acc2[i][j] = fmaf(a[i], b[j], acc2[i][j]);
    }
    __syncthreads();
  }
#pragma unroll
  for (int j = 0; j < 5; ++j) {
    int n2 = tx2 * 5 + j;
    float bias = (n2 >= 40) ? b2[n2 - 40] : 0.f;
#pragma unroll
    for (int i = 0; i < 4; ++i) {
      int gm = row0 + ty2 * 4 + i;
      if (gm < N_NODES) {
        if (n2 < 40) hl[(size_t)gm * 40 + n2] = f2bf(acc2[i][j]);
        else         hrb[(size_t)gm * 40 + (n2 - 40)] = acc2[i][j] + bias;
      }
    }
  }
}

// ---------------- launch ----------------
extern "C" void kernel_launch(void* const* d_in, const int* in_sizes, int n_in,
                              void* d_out, int out_size, void* d_ws, size_t ws_size,
                              hipStream_t stream) {
  const float* x   = (const float*)d_in[0];
  const int* ei    = (const int*)d_in[1];
  const float* W1l = (const float*)d_in[2];
  const float* b1  = (const float*)d_in[3];
  const float* W1r = (const float*)d_in[4];
  const float* W2l = (const float*)d_in[5];
  const float* b2  = (const float*)d_in[6];
  const float* W2r = (const float*)d_in[7];
  float* out = (float*)d_out;
  const int* src = ei;
  const int* dst = ei + N_EDGES;
  (void)in_sizes; (void)n_in; (void)out_size;

  char* w = (char*)d_ws;
  size_t off = 0;
  auto take = [&](size_t bytes) {
    void* p = w + off;
    off = (off + bytes + 255) & ~(size_t)255;
    return p;
  };
  // fast-path layout (~66.5 MB)
  int* cnt    = (int*)take((size_t)N_NODES * 4);
  int* rowptr = (int*)take((size_t)(N_NODES + 1) * 4);
  int* part   = (int*)take(256 * 4);
  int* col    = (int*)take((size_t)N_EDGES * 4);
  unsigned short* hl   = (unsigned short*)take((size_t)N_NODES * 40 * 2);
  unsigned short* xb   = (unsigned short*)take((size_t)N_NODES * 128 * 2);
  unsigned short* aggb = (unsigned short*)take((size_t)N_NODES * 128 * 2);
  unsigned short* w1b  = (unsigned short*)take(128 * 256 * 2);
  unsigned short* w2b  = (unsigned short*)take(80 * 128 * 2);
  unsigned short* hb   = xb; // alias: gemm1 reads own rows, barrier, writes own rows
  bool fast = (off <= ws_size);

  hipMemsetAsync(cnt, 0, (size_t)N_NODES * 4, stream);
  k_count<<<2048, 256, 0, stream>>>(dst, cnt);
  k_scan1<<<SCAN_B, 256, 0, stream>>>(cnt, part);
  k_scan2<<<1, 128, 0, stream>>>(part);
  k_scan3<<<SCAN_B, 256, 0, stream>>>(cnt, part, rowptr);
  k_fill<<<2048, 256, 0, stream>>>(src, dst, rowptr, cnt, col);

  if (fast) {
    k_prepx<<<2048, 256, 0, stream>>>(x, xb);
    k_prepw<<<168, 256, 0, stream>>>(W1l, W1r, W2l, W2r, w1b, w2b);
    k_aggb<<<(N_NODES + 3) / 4, 256, 0, stream>>>(rowptr, col, xb, aggb);
    k_mfma1<<<(N_NODES + 127) / 128, 256, 0, stream>>>(aggb, xb, w1b, b1, hb);
    k_mfma2<<<(N_NODES + 255) / 256, 256, 0, stream>>>(hb, w2b, b2, hl, out);
  } else {
    // fallback layout (~14.5 MB): reuse the front of ws; hl sits where fast-path hl is
    k_fused<<<(N_NODES + 127) / 128, 512, 0, stream>>>(rowptr, col, x, W1l, W1r, b1,
                                                       W2l, W2r, b2, hl, out);
  }
  k_out<<<(N_NODES + 3) / 4, 256, 0, stream>>>(rowptr, col, hl, out, out);
}

// Round 12
// 460.459 us; speedup vs baseline: 2.1052x; 1.2747x over previous
//
#include <hip/hip_runtime.h>
#include <cstdint>

// GraphSAGE 2-layer, MI355X.
// Fast path (ws_size permitting, ~66.5 MB):
//   prep: x -> bf16 (xb), W1/W2 -> packed bf16 (w1b[n][256], w2b[n][128])
//   CSR build (count/scan/fill), k_aggb: 4-edge-parallel bf16 mean-gather (uint4/lane)
//   k_mfma1: hb = relu([aggb|xb] @ w1b^T + b1)  (MFMA bf16, LDS-free; hb aliases xb)
//   k_mfma2: hl(bf16) | hrb(fp32->d_out) = hb @ w2b^T (+b2)
//   k_out  : out = log_softmax(mean_gather(hl) + hrb), 3-edge-parallel gather
// Fallback path (small ws, ~14.5 MB): round-4 fused kernel (proven correct).

#define N_NODES 100000
#define N_EDGES 1600000
#define SCAN_B ((N_NODES + 1023) / 1024) // 98

typedef __attribute__((ext_vector_type(8))) short bf16x8;
typedef __attribute__((ext_vector_type(4))) float f32x4;

static __device__ __forceinline__ unsigned short f2bf(float f) { // RNE
  unsigned int u = __float_as_uint(f);
  return (unsigned short)((u + 0x7fffu + ((u >> 16) & 1u)) >> 16);
}
static __device__ __forceinline__ float bf2f(unsigned short s) {
  return __uint_as_float(((unsigned int)s) << 16);
}
static __device__ __forceinline__ float bflo(unsigned int u) {
  return __uint_as_float(u << 16);
}
static __device__ __forceinline__ float bfhi(unsigned int u) {
  return __uint_as_float(u & 0xffff0000u);
}

// ---------------- CSR build ----------------
__global__ __launch_bounds__(256) void k_count(const int* __restrict__ dst,
                                               int* __restrict__ cnt) {
  int stride = gridDim.x * blockDim.x;
  for (int e = blockIdx.x * blockDim.x + threadIdx.x; e < N_EDGES; e += stride)
    atomicAdd(&cnt[dst[e]], 1);
}

__global__ __launch_bounds__(256) void k_scan1(const int* __restrict__ cnt,
                                               int* __restrict__ part) {
  __shared__ int ts[256];
  int tid = threadIdx.x;
  int base = blockIdx.x * 1024 + tid * 4;
  int s = 0;
#pragma unroll
  for (int j = 0; j < 4; ++j) { int i = base + j; if (i < N_NODES) s += cnt[i]; }
  ts[tid] = s; __syncthreads();
  for (int off = 128; off > 0; off >>= 1) {
    if (tid < off) ts[tid] += ts[tid + off];
    __syncthreads();
  }
  if (tid == 0) part[blockIdx.x] = ts[0];
}

__global__ __launch_bounds__(128) void k_scan2(int* __restrict__ part) {
  __shared__ int ts[128];
  int tid = threadIdx.x;
  int v = (tid < SCAN_B) ? part[tid] : 0;
  ts[tid] = v; __syncthreads();
  for (int off = 1; off < 128; off <<= 1) {
    int add = (tid >= off) ? ts[tid - off] : 0;
    __syncthreads();
    ts[tid] += add;
    __syncthreads();
  }
  if (tid < SCAN_B) part[tid] = ts[tid] - v;
}

__global__ __launch_bounds__(256) void k_scan3(const int* __restrict__ cnt,
                                               const int* __restrict__ part,
                                               int* __restrict__ rowptr) {
  __shared__ int ts[256];
  int tid = threadIdx.x;
  int base = blockIdx.x * 1024 + tid * 4;
  int v[4]; int tsum = 0;
#pragma unroll
  for (int j = 0; j < 4; ++j) { int i = base + j; v[j] = (i < N_NODES) ? cnt[i] : 0; tsum += v[j]; }
  ts[tid] = tsum; __syncthreads();
  for (int off = 1; off < 256; off <<= 1) {
    int add = (tid >= off) ? ts[tid - off] : 0;
    __syncthreads();
    ts[tid] += add;
    __syncthreads();
  }
  int run = part[blockIdx.x] + ts[tid] - tsum;
#pragma unroll
  for (int j = 0; j < 4; ++j) {
    int i = base + j;
    if (i < N_NODES) { run += v[j]; rowptr[i + 1] = run; }
  }
  if (blockIdx.x == 0 && tid == 0) rowptr[0] = 0;
}

__global__ __launch_bounds__(256) void k_fill(const int* __restrict__ src,
                                              const int* __restrict__ dst,
                                              const int* __restrict__ rowptr,
                                              int* __restrict__ cnt,
                                              int* __restrict__ col) {
  int stride = gridDim.x * blockDim.x;
  for (int e = blockIdx.x * blockDim.x + threadIdx.x; e < N_EDGES; e += stride) {
    int d = dst[e];
    int old = atomicAdd(&cnt[d], -1);
    col[rowptr[d] + old - 1] = src[e];
  }
}

// ---------------- fast path: prep ----------------
__global__ __launch_bounds__(256) void k_prepx(const float* __restrict__ x,
                                               unsigned short* __restrict__ xb) {
  int stride = gridDim.x * blockDim.x;
  const int total = N_NODES * 128 / 4;
  for (int i = blockIdx.x * blockDim.x + threadIdx.x; i < total; i += stride) {
    float4 v = ((const float4*)x)[i];
    ushort4 o;
    o.x = f2bf(v.x); o.y = f2bf(v.y); o.z = f2bf(v.z); o.w = f2bf(v.w);
    *(ushort4*)(xb + (size_t)i * 4) = o;
  }
}

// w1b[n][k], n<128, k<256 (k<128: W1l, else W1r); w2b[n][k], n<80, k<128 (n<40: W2l else W2r)
__global__ __launch_bounds__(256) void k_prepw(const float* __restrict__ W1l,
                                               const float* __restrict__ W1r,
                                               const float* __restrict__ W2l,
                                               const float* __restrict__ W2r,
                                               unsigned short* __restrict__ w1b,
                                               unsigned short* __restrict__ w2b) {
  int idx = blockIdx.x * 256 + threadIdx.x; // 168 blocks -> 43008 threads
  if (idx < 32768) {
    int n = idx >> 8, k = idx & 255;
    float v = (k < 128) ? W1l[n * 128 + k] : W1r[n * 128 + (k - 128)];
    w1b[idx] = f2bf(v);
  } else if (idx < 43008) {
    int j = idx - 32768;
    int n = j >> 7, k = j & 127;
    float v = (n < 40) ? W2l[n * 128 + k] : W2r[(n - 40) * 128 + k];
    w2b[j] = f2bf(v);
  }
}

// ---------------- fast path: bf16 mean-gather, 4 edges/wave, uint4 per lane ----------------
// lane = (g = lane>>4: edge slot, q = lane&15: 16B chunk of the 256B row)
// One VMEM instruction fetches 4 edge rows (1KB/wave); unroll x2 -> 8 edges in flight.
__global__ __launch_bounds__(256) void k_aggb(const int* __restrict__ rowptr,
                                              const int* __restrict__ col,
                                              const unsigned short* __restrict__ xb,
                                              unsigned short* __restrict__ aggb) {
  int wv = (blockIdx.x * 256 + threadIdx.x) >> 6;
  int lane = threadIdx.x & 63;
  if (wv >= N_NODES) return;
  int g = lane >> 4, q = lane & 15;
  int s0 = rowptr[wv], s1 = rowptr[wv + 1];
  const uint4* x4 = (const uint4*)xb; // row = 16 x uint4
  float accA[8] = {}, accB[8] = {};
  int e = s0 + g;
  for (; e + 4 < s1; e += 8) {
    uint4 uA = x4[(size_t)col[e] * 16 + q];
    uint4 uB = x4[(size_t)col[e + 4] * 16 + q];
    accA[0] += bflo(uA.x); accA[1] += bfhi(uA.x);
    accA[2] += bflo(uA.y); accA[3] += bfhi(uA.y);
    accA[4] += bflo(uA.z); accA[5] += bfhi(uA.z);
    accA[6] += bflo(uA.w); accA[7] += bfhi(uA.w);
    accB[0] += bflo(uB.x); accB[1] += bfhi(uB.x);
    accB[2] += bflo(uB.y); accB[3] += bfhi(uB.y);
    accB[4] += bflo(uB.z); accB[5] += bfhi(uB.z);
    accB[6] += bflo(uB.w); accB[7] += bfhi(uB.w);
  }
  if (e < s1) {
    uint4 uA = x4[(size_t)col[e] * 16 + q];
    accA[0] += bflo(uA.x); accA[1] += bfhi(uA.x);
    accA[2] += bflo(uA.y); accA[3] += bfhi(uA.y);
    accA[4] += bflo(uA.z); accA[5] += bfhi(uA.z);
    accA[6] += bflo(uA.w); accA[7] += bfhi(uA.w);
  }
#pragma unroll
  for (int i = 0; i < 8; ++i) {
    float v = accA[i] + accB[i];
    v += __shfl_xor(v, 16);
    v += __shfl_xor(v, 32);
    accA[i] = v; // lanes 0..15 (g==0) hold full sums
  }
  if (lane < 16) {
    float inv = 1.f / (float)max(s1 - s0, 1);
    uint4 o;
    o.x = (unsigned int)f2bf(accA[0] * inv) | ((unsigned int)f2bf(accA[1] * inv) << 16);
    o.y = (unsigned int)f2bf(accA[2] * inv) | ((unsigned int)f2bf(accA[3] * inv) << 16);
    o.z = (unsigned int)f2bf(accA[4] * inv) | ((unsigned int)f2bf(accA[5] * inv) << 16);
    o.w = (unsigned int)f2bf(accA[6] * inv) | ((unsigned int)f2bf(accA[7] * inv) << 16);
    ((uint4*)aggb)[(size_t)wv * 16 + q] = o;
  }
}

// ---------------- fast path: MFMA GEMM1  hb = relu([aggb|xb] @ w1b^T + b1) ----------------
// LDS-free: A/B fragments read straight from global (L1/L2-hot). hb aliases xb ->
// __syncthreads() separates all reads from all writes within the owning block;
// each block touches only its own 128-row panel (tail clamp stays in-panel).
__global__ __launch_bounds__(256) void k_mfma1(const unsigned short* __restrict__ aggb,
                                               const unsigned short* __restrict__ xb,
                                               const unsigned short* __restrict__ w1b,
                                               const float* __restrict__ b1,
                                               unsigned short* __restrict__ hb) {
  int tid = threadIdx.x;
  int wid = tid >> 6, lane = tid & 63;
  int wr = wid >> 1, wc = wid & 1;
  int lr = lane & 15, lg = lane >> 4;
  int row0 = blockIdx.x * 128 + wr * 64;
  int wn = wc * 64;

  size_t arow[4];
#pragma unroll
  for (int m = 0; m < 4; ++m) {
    int gm = row0 + m * 16 + lr;
    if (gm > N_NODES - 1) gm = N_NODES - 1;
    arow[m] = (size_t)gm * 128;
  }
  f32x4 acc[4][4] = {};
#pragma unroll
  for (int k0 = 0; k0 < 256; k0 += 32) {
    const unsigned short* ab = (k0 < 128) ? (aggb + k0) : (xb + (k0 - 128));
    bf16x8 a[4], b[4];
#pragma unroll
    for (int m = 0; m < 4; ++m)
      a[m] = *(const bf16x8*)(ab + arow[m] + lg * 8);
#pragma unroll
    for (int n = 0; n < 4; ++n)
      b[n] = *(const bf16x8*)(w1b + (size_t)(wn + n * 16 + lr) * 256 + k0 + lg * 8);
#pragma unroll
    for (int m = 0; m < 4; ++m)
#pragma unroll
      for (int n = 0; n < 4; ++n)
        acc[m][n] = __builtin_amdgcn_mfma_f32_16x16x32_bf16(a[m], b[n], acc[m][n], 0, 0, 0);
  }
  __syncthreads(); // hb aliases xb: drain all A reads before any write
  float bb[4];
#pragma unroll
  for (int n = 0; n < 4; ++n) bb[n] = b1[wn + n * 16 + lr];
#pragma unroll
  for (int m = 0; m < 4; ++m)
#pragma unroll
    for (int r = 0; r < 4; ++r) {
      int gm = row0 + m * 16 + lg * 4 + r; // C/D: row=(lane>>4)*4+reg, col=lane&15
      if (gm < N_NODES) {
#pragma unroll
        for (int n = 0; n < 4; ++n) {
          float v = fmaxf(acc[m][n][r] + bb[n], 0.f);
          hb[(size_t)gm * 128 + wn + n * 16 + lr] = f2bf(v);
        }
      }
    }
}

// ---------------- fast path: MFMA GEMM2  [hl | hrb] = hb @ w2b^T (+b2) ----------------
__global__ __launch_bounds__(256) void k_mfma2(const unsigned short* __restrict__ hb,
                                               const unsigned short* __restrict__ w2b,
                                               const float* __restrict__ b2,
                                               unsigned short* __restrict__ hl,
                                               float* __restrict__ outp) {
  int tid = threadIdx.x;
  int wid = tid >> 6, lane = tid & 63;
  int lr = lane & 15, lg = lane >> 4;
  int row0 = blockIdx.x * 256 + wid * 64;

  size_t arow[4];
#pragma unroll
  for (int m = 0; m < 4; ++m) {
    int gm = row0 + m * 16 + lr;
    if (gm > N_NODES - 1) gm = N_NODES - 1;
    arow[m] = (size_t)gm * 128;
  }
  f32x4 acc[4][5] = {};
#pragma unroll
  for (int k0 = 0; k0 < 128; k0 += 32) {
    bf16x8 a[4], b[5];
#pragma unroll
    for (int m = 0; m < 4; ++m)
      a[m] = *(const bf16x8*)(hb + arow[m] + k0 + lg * 8);
#pragma unroll
    for (int n = 0; n < 5; ++n)
      b[n] = *(const bf16x8*)(w2b + (size_t)(n * 16 + lr) * 128 + k0 + lg * 8);
#pragma unroll
    for (int m = 0; m < 4; ++m)
#pragma unroll
      for (int n = 0; n < 5; ++n)
        acc[m][n] = __builtin_amdgcn_mfma_f32_16x16x32_bf16(a[m], b[n], acc[m][n], 0, 0, 0);
  }
#pragma unroll
  for (int m = 0; m < 4; ++m)
#pragma unroll
    for (int r = 0; r < 4; ++r) {
      int gm = row0 + m * 16 + lg * 4 + r;
      if (gm < N_NODES) {
#pragma unroll
        for (int n = 0; n < 5; ++n) {
          int c = n * 16 + lr;
          float v = acc[m][n][r];
          if (c < 40) hl[(size_t)gm * 40 + c] = f2bf(v);
          else        outp[(size_t)gm * 40 + (c - 40)] = v + b2[c - 40];
        }
      }
    }
}

// ---------------- out = log_softmax(mean_gather(hl) + hrb), hrb aliases out ----------------
// lane = (g = lane/20: edge slot 0..2, cp = lane%20: channel-pair). One VMEM instr
// fetches 3 edge rows (240B); unroll x2 -> 6 edges in flight. Cross-group reduce via
// indexed shfl, then redistribute to 40-lane layout for the softmax.
__global__ __launch_bounds__(256) void k_out(const int* __restrict__ rowptr,
                                             const int* __restrict__ col,
                                             const unsigned short* __restrict__ hl,
                                             const float* __restrict__ hrb,
                                             float* __restrict__ out) {
  int wid = (blockIdx.x * 256 + threadIdx.x) >> 6;
  int lane = threadIdx.x & 63;
  if (wid >= N_NODES) return;
  int g = lane / 20, cp = lane % 20; // g==3 (lanes 60..63) idle
  int s0 = rowptr[wid], s1 = rowptr[wid + 1];
  const unsigned int* hl2 = (const unsigned int*)hl; // row = 20 uints
  float ax = 0.f, ay = 0.f, bx = 0.f, by = 0.f;
  int e = (g < 3) ? (s0 + g) : s1;
  for (; e + 3 < s1; e += 6) {
    unsigned int u0 = hl2[(size_t)col[e] * 20 + cp];
    unsigned int u1 = hl2[(size_t)col[e + 3] * 20 + cp];
    ax += bflo(u0); ay += bfhi(u0);
    bx += bflo(u1); by += bfhi(u1);
  }
  if (e < s1) {
    unsigned int u0 = hl2[(size_t)col[e] * 20 + cp];
    ax += bflo(u0); ay += bfhi(u0);
  }
  float px = ax + bx, py = ay + by;
  // sum across groups 0,1,2 (result meaningful on lanes 0..19)
  float sx = px + __shfl(px, cp + 20) + __shfl(px, cp + 40);
  float sy = py + __shfl(py, cp + 20) + __shfl(py, cp + 40);
  // redistribute: lane c (<40) takes channel c from pair c>>1
  float gx = __shfl(sx, lane >> 1);
  float gy = __shfl(sy, lane >> 1);
  float sum = (lane & 1) ? gy : gx;

  float inv = 1.f / (float)max(s1 - s0, 1);
  float v = (lane < 40) ? (sum * inv + hrb[(size_t)wid * 40 + lane]) : -3.4e38f;
  float mv = v;
#pragma unroll
  for (int off = 32; off > 0; off >>= 1) mv = fmaxf(mv, __shfl_xor(mv, off));
  float ev = (lane < 40) ? __expf(v - mv) : 0.f;
  float sv = ev;
#pragma unroll
  for (int off = 32; off > 0; off >>= 1) sv += __shfl_xor(sv, off);
  if (lane < 40) out[(size_t)wid * 40 + lane] = v - mv - __logf(sv);
}

// ---------------- fallback: round-4 fused kernel (proven) ----------------
__global__ __launch_bounds__(512) void k_fused(const int* __restrict__ rowptr,
                                               const int* __restrict__ col,
                                               const float* __restrict__ x,
                                               const float* __restrict__ W1l,
                                               const float* __restrict__ W1r,
                                               const float* __restrict__ b1,
                                               const float* __restrict__ W2l,
                                               const float* __restrict__ W2r,
                                               const float* __restrict__ b2,
                                               unsigned short* __restrict__ hl,
                                               float* __restrict__ hrb) {
  __shared__ float Hs[128][132];
  __shared__ float S1[32][132];
  __shared__ float S2[32][132];
  int tid = threadIdx.x;
  int row0 = blockIdx.x * 128;
  {
    int wv = tid >> 6, lane = tid & 63;
    const float2* x2 = (const float2*)x;
    for (int r = 0; r < 16; ++r) {
      int m = wv * 16 + r;
      int gm = row0 + m;
      float2 a0 = make_float2(0.f, 0.f), a1 = make_float2(0.f, 0.f);
      float inv = 0.f;
      if (gm < N_NODES) {
        int s0 = rowptr[gm], s1 = rowptr[gm + 1];
        int e = s0;
        for (; e + 1 < s1; e += 2) {
          int sA = col[e], sB = col[e + 1];
          float2 vA = x2[(size_t)sA * 64 + lane];
          float2 vB = x2[(size_t)sB * 64 + lane];
          a0.x += vA.x; a0.y += vA.y;
          a1.x += vB.x; a1.y += vB.y;
        }
        if (e < s1) {
          float2 vA = x2[(size_t)col[e] * 64 + lane];
          a0.x += vA.x; a0.y += vA.y;
        }
        inv = 1.f / (float)max(s1 - s0, 1);
      }
      Hs[2 * lane + 0][m] = (a0.x + a1.x) * inv;
      Hs[2 * lane + 1][m] = (a0.y + a1.y) * inv;
    }
  }
  __syncthreads();
  int tx = tid & 31, ty = tid >> 5;
  float acc1[8][4] = {};
  for (int k0 = 0; k0 < 256; k0 += 32) {
    const float* Wp = (k0 < 128) ? W1l : W1r;
    int kb = (k0 < 128) ? k0 : (k0 - 128);
#pragma unroll
    for (int r = 0; r < 2; ++r) {
      int idx = tid + r * 512;
      int n = idx >> 3, q = idx & 7;
      float4 v = *(const float4*)(Wp + n * 128 + kb + q * 4);
      S2[q * 4 + 0][n] = v.x; S2[q * 4 + 1][n] = v.y;
      S2[q * 4 + 2][n] = v.z; S2[q * 4 + 3][n] = v.w;
    }
    if (k0 >= 128) {
#pragma unroll
      for (int r = 0; r < 2; ++r) {
        int idx = tid + r * 512;
        int m = idx >> 3, q = idx & 7;
        int gm = row0 + m; if (gm >= N_NODES) gm = N_NODES - 1;
        float4 v = *(const float4*)(x + (size_t)gm * 128 + (k0 - 128) + q * 4);
        S1[q * 4 + 0][m] = v.x; S1[q * 4 + 1][m] = v.y;
        S1[q * 4 + 2][m] = v.z; S1[q * 4 + 3][m] = v.w;
      }
    }
    __syncthreads();
#pragma unroll 4
    for (int k = 0; k < 32; ++k) {
      const float* arow = (k0 < 128) ? &Hs[k0 + k][0] : &S1[k][0];
      float a[8], b[4];
      *(float4*)&a[0] = *(const float4*)(arow + ty * 8);
      *(float4*)&a[4] = *(const float4*)(arow + ty * 8 + 4);
      *(float4*)&b[0] = *(const float4*)&S2[k][tx * 4];
#pragma unroll
      for (int i = 0; i < 8; ++i)
#pragma unroll
        for (int j = 0; j < 4; ++j)
          acc1[i][j] = fmaf(a[i], b[j], acc1[i][j]);
    }
    __syncthreads();
  }
  {
    float4 bl = *(const float4*)(b1 + tx * 4);
    float bb[4] = {bl.x, bl.y, bl.z, bl.w};
#pragma unroll
    for (int j = 0; j < 4; ++j) {
      int n = tx * 4 + j;
      float4 lo, hi;
      lo.x = fmaxf(acc1[0][j] + bb[j], 0.f); lo.y = fmaxf(acc1[1][j] + bb[j], 0.f);
      lo.z = fmaxf(acc1[2][j] + bb[j], 0.f); lo.w = fmaxf(acc1[3][j] + bb[j], 0.f);
      hi.x = fmaxf(acc1[4][j] + bb[j], 0.f); hi.y = fmaxf(acc1[5][j] + bb[j], 0.f);
      hi.z = fmaxf(acc1[6][j] + bb[j], 0.f); hi.w = fmaxf(acc1[7][j] + bb[j], 0.f);
      *(float4*)&Hs[n][ty * 8] = lo;
      *(float4*)&Hs[n][ty * 8 + 4] = hi;
    }
  }
  int tx2 = tid & 15, ty2 = tid >> 4;
  float acc2[4][5] = {};
  for (int k0 = 0; k0 < 128; k0 += 32) {
#pragma unroll
    for (int r = 0; r < 2; ++r) {
      int idx = tid + r * 512;
      if (idx < 640) {
        int n2 = idx >> 3, q = idx & 7;
        const float* Bp = (n2 < 40) ? (W2l + n2 * 128) : (W2r + (n2 - 40) * 128);
        float4 v = *(const float4*)(Bp + k0 + q * 4);
        S2[q * 4 + 0][n2] = v.x; S2[q * 4 + 1][n2] = v.y;
        S2[q * 4 + 2][n2] = v.z; S2[q * 4 + 3][n2] = v.w;
      }
    }
    __syncthreads();
#pragma unroll 4
    for (int k = 0; k < 32; ++k) {
      float a[4], b[5];
      *(float4*)&a[0] = *(const float4*)&Hs[k0 + k][ty2 * 4];
#pragma unroll
      for (int j = 0; j < 5; ++j) b[j] = S2[k][tx2 * 5 + j];
#pragma unroll
      for (int i = 0; i < 4; ++i)
#pragma unroll
        for (int j = 0; j < 5; ++j)
          acc2[i][j] = fmaf(a[i], b[j], acc2[i][j]);
    }
    __syncthreads();
  }
#pragma unroll
  for (int j = 0; j < 5; ++j) {
    int n2 = tx2 * 5 + j;
    float bias = (n2 >= 40) ? b2[n2 - 40] : 0.f;
#pragma unroll
    for (int i = 0; i < 4; ++i) {
      int gm = row0 + ty2 * 4 + i;
      if (gm < N_NODES) {
        if (n2 < 40) hl[(size_t)gm * 40 + n2] = f2bf(acc2[i][j]);
        else         hrb[(size_t)gm * 40 + (n2 - 40)] = acc2[i][j] + bias;
      }
    }
  }
}

// ---------------- launch ----------------
extern "C" void kernel_launch(void* const* d_in, const int* in_sizes, int n_in,
                              void* d_out, int out_size, void* d_ws, size_t ws_size,
                              hipStream_t stream) {
  const float* x   = (const float*)d_in[0];
  const int* ei    = (const int*)d_in[1];
  const float* W1l = (const float*)d_in[2];
  const float* b1  = (const float*)d_in[3];
  const float* W1r = (const float*)d_in[4];
  const float* W2l = (const float*)d_in[5];
  const float* b2  = (const float*)d_in[6];
  const float* W2r = (const float*)d_in[7];
  float* out = (float*)d_out;
  const int* src = ei;
  const int* dst = ei + N_EDGES;
  (void)in_sizes; (void)n_in; (void)out_size;

  char* w = (char*)d_ws;
  size_t off = 0;
  auto take = [&](size_t bytes) {
    void* p = w + off;
    off = (off + bytes + 255) & ~(size_t)255;
    return p;
  };
  // fast-path layout (~66.5 MB)
  int* cnt    = (int*)take((size_t)N_NODES * 4);
  int* rowptr = (int*)take((size_t)(N_NODES + 1) * 4);
  int* part   = (int*)take(256 * 4);
  int* col    = (int*)take((size_t)N_EDGES * 4);
  unsigned short* hl   = (unsigned short*)take((size_t)N_NODES * 40 * 2);
  unsigned short* xb   = (unsigned short*)take((size_t)N_NODES * 128 * 2);
  unsigned short* aggb = (unsigned short*)take((size_t)N_NODES * 128 * 2);
  unsigned short* w1b  = (unsigned short*)take(128 * 256 * 2);
  unsigned short* w2b  = (unsigned short*)take(80 * 128 * 2);
  unsigned short* hb   = xb; // alias: gemm1 reads own rows, barrier, writes own rows
  bool fast = (off <= ws_size);

  hipMemsetAsync(cnt, 0, (size_t)N_NODES * 4, stream);
  k_count<<<2048, 256, 0, stream>>>(dst, cnt);
  k_scan1<<<SCAN_B, 256, 0, stream>>>(cnt, part);
  k_scan2<<<1, 128, 0, stream>>>(part);
  k_scan3<<<SCAN_B, 256, 0, stream>>>(cnt, part, rowptr);
  k_fill<<<2048, 256, 0, stream>>>(src, dst, rowptr, cnt, col);

  if (fast) {
    k_prepx<<<2048, 256, 0, stream>>>(x, xb);
    k_prepw<<<168, 256, 0, stream>>>(W1l, W1r, W2l, W2r, w1b, w2b);
    k_aggb<<<(N_NODES + 3) / 4, 256, 0, stream>>>(rowptr, col, xb, aggb);
    k_mfma1<<<(N_NODES + 127) / 128, 256, 0, stream>>>(aggb, xb, w1b, b1, hb);
    k_mfma2<<<(N_NODES + 255) / 256, 256, 0, stream>>>(hb, w2b, b2, hl, out);
  } else {
    // fallback layout (~14.5 MB): reuse the front of ws; hl sits where fast-path hl is
    k_fused<<<(N_NODES + 127) / 128, 512, 0, stream>>>(rowptr, col, x, W1l, W1r, b1,
                                                       W2l, W2r, b2, hl, out);
  }
  k_out<<<(N_NODES + 3) / 4, 256, 0, stream>>>(rowptr, col, hl, out, out);
}